// Round 11
// baseline (491.338 us; speedup 1.0000x reference)
//
#include <hip/hip_runtime.h>
#include <hip/hip_bf16.h>

// SpatialBranch: 1088 box-pair indicator maps -> conv1(2->64,5x5)+pool2 ->
// conv2(64->32,5x5)+pool2 -> spatial mean -> FC(32->512)+ReLU, plus slicing.
//
// Round 11 changes (R10 fp4 failed numerically at 0.3223 vs 0.32; revert to fp8
// numerics but keep the 3-blocks/CU occupancy goal):
//  - SPLIT-K double pass: pass P covers ch [32P,32P+32). Only half of h1 is
//    resident (2 planes x 904x16B = 28.9KB); pass-B phase-1 overwrites it after
//    pass-A MFMAs. K-order per step s: kk=h*32+b, tap=2s+(b>>4),
//    ch=32P+16h+(b&15) -> A = two ds_read_b128 with UNIFORM tap immediates
//    (lane h selects plane only), B-frags rebuilt to match (26 steps; step 12's
//    2nd tap zero-padded in B, A re-reads tap-24 rows: valid x 0).
//  - LDS 47.4KB -> 3 blocks/CU (6 waves/SIMD). B-prefetch 2-deep (VGPR cap 85).
//  - Keeps R9: fp8 MX MFMA, tiered phase-1, compact tiles, c2T epilogue,
//    tile-aligned zero-row trim, bias folding.

#define NPAIRS 1088
#define FEAT_SZ (NPAIRS * 512)

typedef float f32x16 __attribute__((ext_vector_type(16)));
typedef int v8i __attribute__((ext_vector_type(8)));
typedef float floatx2 __attribute__((ext_vector_type(2)));

// workspace layout (bytes)
#define WS_V 0            // V fp8 [200 rows][72 B] = 14400 (rows: c*100+sy*10+sx)
#define WS_C2B 14400      // 32 f32 (conv1-bias folded through conv2)
#define WS_BFRAG 14528    // 26 steps x 64 lanes x 32B fp8 = 53248
// total 67776 bytes of ws

// LDS layout (bytes)
#define H1_PLANE 14464    // one plane: 904 rows x 16B (16 ch fp8 of current pass)
                          // planes h=0,1 -> [0, 28928)
#define SM_V 28928        // V fp8 [200][72] = 14400 -> [28928, 43328)
                          // phase>=3: c2T [32][706] bf16 = 45184 aliases [0,45184)
#define SM_HM 45184       // h_mean [32] f32
#define SM_PART 45312     // partial [16][32] f32 = 2048
#define SMEM_BYTES 47360

__device__ __forceinline__ unsigned short f2bf(float f) {
  __hip_bfloat16 h = __float2bfloat16(f);
  unsigned short u;
  __builtin_memcpy(&u, &h, 2);
  return u;
}
__device__ __forceinline__ float bflo(unsigned int u) { return __uint_as_float(u << 16); }
__device__ __forceinline__ float bfhi(unsigned int u) { return __uint_as_float(u & 0xffff0000u); }

__device__ __forceinline__ void fp8x8_to_f32(uint2 u, float* f) {
  floatx2 t;
  t = __builtin_amdgcn_cvt_pk_f32_fp8((int)u.x, false); f[0] = t.x; f[1] = t.y;
  t = __builtin_amdgcn_cvt_pk_f32_fp8((int)u.x, true);  f[2] = t.x; f[3] = t.y;
  t = __builtin_amdgcn_cvt_pk_f32_fp8((int)u.y, false); f[4] = t.x; f[5] = t.y;
  t = __builtin_amdgcn_cvt_pk_f32_fp8((int)u.y, true);  f[6] = t.x; f[7] = t.y;
}

__device__ __forceinline__ unsigned pack_fp8x4(float a, float b, float c, float d) {
  unsigned q = 0;
  q = __builtin_amdgcn_cvt_pk_fp8_f32(a, b, q, false);
  q = __builtin_amdgcn_cvt_pk_fp8_f32(c, d, q, true);
  return q;
}

__device__ __forceinline__ void pair_ij(int k, int* pi, int* pj) {
  int i = 0, rem = k;
  while (rem >= 16 - i) { rem -= 16 - i; ++i; }
  *pi = i;
  *pj = i + 1 + rem;
}

// window state for coordinate z vs interval [a,b): 0 empty, 1..4 left-partial
// (k0=s,k1=5), 5 full, 6..9 right-partial (k0=0,k1=s-5). Valid since b-a>=4.
__device__ __forceinline__ int stz(int z, int a, int b) {
  if (z >= a) {
    if (z >= b) return 0;
    if (z <= b - 5) return 5;
    return 5 + (b - z);
  }
  if (z >= a - 4) return a - z;
  return 0;
}

__global__ void prep_kernel(const float* __restrict__ w1, const float* __restrict__ b1,
                            const float* __restrict__ w2, float* __restrict__ out,
                            unsigned char* __restrict__ ws) {
  int tid = blockIdx.x * blockDim.x + threadIdx.x;

  if (tid < 12800) {
    // V[c][sy][sx][o] fp8: conv1 response of window-state (sy,sx) = rect subsum
    int o = tid & 63;
    int q = tid >> 6;
    int sx = q % 10; q /= 10;
    int sy = q % 10;
    int c = q / 10;
    int ky0 = (sy <= 4) ? sy : 0;
    int ky1 = (sy == 0) ? 0 : ((sy <= 5) ? 5 : sy - 5);
    int kx0 = (sx <= 4) ? sx : 0;
    int kx1 = (sx == 0) ? 0 : ((sx <= 5) ? 5 : sx - 5);
    const float* w = w1 + (o * 2 + c) * 25;
    float v = 0.f;
    for (int ky = ky0; ky < ky1; ++ky)
      for (int kx = kx0; kx < kx1; ++kx) v += w[ky * 5 + kx];
    unsigned qv = __builtin_amdgcn_cvt_pk_fp8_f32(v, v, 0, false);
    ((unsigned char*)(ws + WS_V))[(c * 100 + sy * 10 + sx) * 72 + o] = (unsigned char)(qv & 0xFF);
  } else if (tid < 12832) {
    // C2B[oc] = sum_ic b1[ic] * sum_tap w2[oc][ic][tap]
    int oc = tid - 12800;
    float s = 0.f;
    for (int ic = 0; ic < 64; ++ic) {
      const float* wp = w2 + (oc * 64 + ic) * 25;
      float t = 0.f;
      for (int q2 = 0; q2 < 25; ++q2) t += wp[q2];
      s += b1[ic] * t;
    }
    ((float*)(ws + WS_C2B))[oc] = s;
  } else if (tid < 13920) {
    // slicing output (as float values; d_out read back as float32)
    int p = tid - 12832;
    int b = p / 136, k = p % 136, i, j;
    pair_ij(k, &i, &j);
    out[FEAT_SZ + p * 3 + 0] = (float)b;
    out[FEAT_SZ + p * 3 + 1] = (float)i;
    out[FEAT_SZ + p * 3 + 2] = (float)j;
  } else if (tid < 27232) {
    // conv2 B fragments (fp8) for split-K: step = P*13 + s covers taps 2s,2s+1
    // of ch [32P,32P+32). Lane l: n=l&31, h=l>>5. Operand byte b (0..31):
    // tap = 2s + (b>>4), ch = 32P + 16h + (b&15). Step 12: tap 25 -> zeros.
    int idx = tid - 13920;          // [0, 13312)
    int d = idx & 7;
    int lane = (idx >> 3) & 63;
    int step = idx >> 9;            // 0..25
    int P = step >= 13 ? 1 : 0;
    int s = step - P * 13;
    int n = lane & 31, h = lane >> 5;
    int tap = 2 * s + (d >> 2);
    int chb = P * 32 + h * 16 + ((4 * d) & 15);
    unsigned q = 0;
    if (tap < 25) {
      float v0 = w2[(n * 64 + chb + 0) * 25 + tap];
      float v1 = w2[(n * 64 + chb + 1) * 25 + tap];
      float v2 = w2[(n * 64 + chb + 2) * 25 + tap];
      float v3 = w2[(n * 64 + chb + 3) * 25 + tap];
      q = pack_fp8x4(v0, v1, v2, v3);
    }
    ((unsigned*)(ws + WS_BFRAG))[step * 512 + lane * 8 + d] = q;
  }
}

__global__ __launch_bounds__(512, 6) void main_kernel(
    const float* __restrict__ bboxes, const float* __restrict__ b2,
    const float* __restrict__ fcw, const float* __restrict__ fcb,
    const unsigned char* __restrict__ ws, float* __restrict__ out) {
  __shared__ __align__(16) unsigned char smem[SMEM_BYTES];
  const int tid = threadIdx.x;
  const int lane = tid & 63;
  const int wid = tid >> 6;
  const int p = blockIdx.x;

  // ---- stage V table into LDS (14400 B, coalesced) ----
  {
    const uint4* Vsrc = (const uint4*)(ws + WS_V);
    uint4* Vdst = (uint4*)(smem + SM_V);
    for (int i = tid; i < 900; i += 512) Vdst[i] = Vsrc[i];
  }

  // ---- pair constants (uniform; overlaps the V copy) ----
  int b = p / 136, k = p % 136, bi, bj;
  pair_ij(k, &bi, &bj);
  const float* bbA = bboxes + (b * 17 + bi) * 4;
  const float* bbB = bboxes + (b * 17 + bj) * 4;
  int ax[2], ay[2], bx[2], by[2];
  {
    auto cl = [](float v) { int t = (int)ceilf(v); return t < 0 ? 0 : (t > 64 ? 64 : t); };
    ax[0] = cl(bbA[0]); ay[0] = cl(bbA[1]); bx[0] = cl(bbA[2]); by[0] = cl(bbA[3]);
    ax[1] = cl(bbB[0]); ay[1] = cl(bbB[1]); bx[1] = cl(bbB[2]); by[1] = cl(bbB[3]);
  }

  // active conv2 output row range (h1 zero outside support; bias folded -> valid skip)
  int s0a = ay[0] - 4 < 0 ? 0 : ay[0] - 4;
  int s0b = ay[1] - 4 < 0 ? 0 : ay[1] - 4;
  int pre0 = s0a < s0b ? s0a : s0b;
  int e0a = by[0] < 60 ? by[0] : 60;
  int e0b = by[1] < 60 ? by[1] : 60;
  int pre1 = e0a > e0b ? e0a : e0b;
  int pr0 = pre0 >> 1, pr1 = (pre1 - 1) >> 1;
  int or0 = pr0 - 4 < 0 ? 0 : pr0 - 4;
  int or1 = pr1 > 25 ? 25 : pr1;
  int poslo = or0 * 26, poshi = (or1 + 1) * 26;
  int t_first = poslo >> 5;
  int t_last = (poshi - 1) >> 5;  // <= 21

  // h1 rows phase 2 actually reads (TILE-ALIGNED pos range; R7 lesson)
  int pos_end = (t_last + 1) * 32; if (pos_end > 676) pos_end = 676;
  int zr0 = (t_first * 32) / 26;
  int zr1 = (pos_end - 1) / 26 + 4; if (zr1 > 29) zr1 = 29;

  // compact assignment over active tiles: t = t_first + wid + ti*8
  const int oc = lane & 31;
  int tb[3]; int acts[3]; unsigned vb[3]; bool anyact = false;
  const unsigned hvo = (unsigned)(lane >> 5) * H1_PLANE;
#pragma unroll
  for (int ti = 0; ti < 3; ++ti) {
    int t = t_first + wid + ti * 8;
    bool a = (t <= t_last);
    acts[ti] = __builtin_amdgcn_readfirstlane(a ? 1 : 0);  // wave-uniform -> SGPR
    anyact |= a;
    tb[ti] = t * 32;
    int pos = tb[ti] + (lane & 31);
    if (pos > 675) pos = 675;
    int oy2 = pos / 26, ox2 = pos - oy2 * 26;
    vb[ti] = (unsigned)(oy2 * 30 + ox2) * 16u + hvo;  // inactive: never read
  }

  f32x16 acc[3];
#pragma unroll
  for (int ti = 0; ti < 3; ++ti)
#pragma unroll
    for (int r = 0; r < 16; ++r) acc[ti][r] = 0.f;

  // ---- phase 1 (per pass P): conv1+pool1 for ch [32P,32P+32) -> 2 planes ----
  auto phase1 = [&](int P) {
    const unsigned vB = (unsigned)(P * 32);
    for (int pos = tid; pos < 900; pos += 512) {
      int py = pos / 30;
      if (py < zr0 || py > zr1) continue;  // never read by phase 2
      int px = pos - py * 30;
      int oy = py * 2, ox = px * 2;
      int sy[2][2], sx[2][2];
#pragma unroll
      for (int c = 0; c < 2; ++c) {
        sy[c][0] = stz(oy, ay[c], by[c]);
        sy[c][1] = stz(oy + 1, ay[c], by[c]);
        sx[c][0] = stz(ox, ax[c], bx[c]);
        sx[c][1] = stz(ox + 1, ax[c], bx[c]);
      }
      bool e0 = ((sy[0][0] | sy[0][1]) == 0) || ((sx[0][0] | sx[0][1]) == 0);
      bool e1 = ((sy[1][0] | sy[1][1]) == 0) || ((sx[1][0] | sx[1][1]) == 0);
      unsigned hb = (unsigned)pos * 16u;

      if (e0 && e1) {
        *(uint4*)(smem + 0 * H1_PLANE + hb) = make_uint4(0u, 0u, 0u, 0u);
        *(uint4*)(smem + 1 * H1_PLANE + hb) = make_uint4(0u, 0u, 0u, 0u);
        continue;
      }

      uint2 qd[4];  // 8 ch per dword-pair; g8 covers ch 32P + 8*g8 + 0..7
      if (e0 || e1) {
        // ---- single active channel ----
        int c = e0 ? 1 : 0;
        unsigned ro[4];
#pragma unroll
        for (int dy = 0; dy < 2; ++dy)
#pragma unroll
          for (int dx = 0; dx < 2; ++dx)
            ro[dy * 2 + dx] =
                SM_V + (unsigned)c * 7200u + (unsigned)(sy[c][dy] * 10 + sx[c][dx]) * 72u;
        bool same = (ro[1] == ro[0]) & (ro[2] == ro[0]) & (ro[3] == ro[0]);
        if (same) {
          // h1 bytes == V bytes (other channel adds exact 0; requant roundtrip)
#pragma unroll
          for (int g8 = 0; g8 < 4; ++g8)
            qd[g8] = *(const uint2*)(smem + ro[0] + vB + g8 * 8u);
        } else {
#pragma unroll
          for (int g8 = 0; g8 < 4; ++g8) {
            float mx[8];
#pragma unroll
            for (int sp = 0; sp < 4; ++sp) {
              uint2 u = *(const uint2*)(smem + ro[sp] + vB + g8 * 8u);
              float a[8];
              fp8x8_to_f32(u, a);
#pragma unroll
              for (int d = 0; d < 8; ++d)
                mx[d] = (sp == 0) ? a[d] : fmaxf(mx[d], a[d]);
            }
            qd[g8].x = pack_fp8x4(mx[0], mx[1], mx[2], mx[3]);
            qd[g8].y = pack_fp8x4(mx[4], mx[5], mx[6], mx[7]);
          }
        }
      } else {
        // ---- both channels active ----
        unsigned r0o[4], r1o[4];
#pragma unroll
        for (int dy = 0; dy < 2; ++dy)
#pragma unroll
          for (int dx = 0; dx < 2; ++dx) {
            r0o[dy * 2 + dx] = SM_V + (unsigned)(sy[0][dy] * 10 + sx[0][dx]) * 72u;
            r1o[dy * 2 + dx] = SM_V + 7200u + (unsigned)(sy[1][dy] * 10 + sx[1][dx]) * 72u;
          }
        bool sameAB = (r0o[1] == r0o[0]) & (r0o[2] == r0o[0]) & (r0o[3] == r0o[0]) &
                      (r1o[1] == r1o[0]) & (r1o[2] == r1o[0]) & (r1o[3] == r1o[0]);
        if (sameAB) {
#pragma unroll
          for (int g8 = 0; g8 < 4; ++g8) {
            uint2 u0 = *(const uint2*)(smem + r0o[0] + vB + g8 * 8u);
            uint2 u1 = *(const uint2*)(smem + r1o[0] + vB + g8 * 8u);
            float a[8], c[8];
            fp8x8_to_f32(u0, a);
            fp8x8_to_f32(u1, c);
            qd[g8].x = pack_fp8x4(a[0] + c[0], a[1] + c[1], a[2] + c[2], a[3] + c[3]);
            qd[g8].y = pack_fp8x4(a[4] + c[4], a[5] + c[5], a[6] + c[6], a[7] + c[7]);
          }
        } else {
#pragma unroll
          for (int g8 = 0; g8 < 4; ++g8) {
            float mx[8];
#pragma unroll
            for (int sp = 0; sp < 4; ++sp) {
              uint2 u0 = *(const uint2*)(smem + r0o[sp] + vB + g8 * 8u);
              uint2 u1 = *(const uint2*)(smem + r1o[sp] + vB + g8 * 8u);
              float a[8], c[8];
              fp8x8_to_f32(u0, a);
              fp8x8_to_f32(u1, c);
#pragma unroll
              for (int d = 0; d < 8; ++d) {
                float v = a[d] + c[d];
                mx[d] = (sp == 0) ? v : fmaxf(mx[d], v);
              }
            }
            qd[g8].x = pack_fp8x4(mx[0], mx[1], mx[2], mx[3]);
            qd[g8].y = pack_fp8x4(mx[4], mx[5], mx[6], mx[7]);
          }
        }
      }
      *(uint4*)(smem + 0 * H1_PLANE + hb) = make_uint4(qd[0].x, qd[0].y, qd[1].x, qd[1].y);
      *(uint4*)(smem + 1 * H1_PLANE + hb) = make_uint4(qd[2].x, qd[2].y, qd[3].x, qd[3].y);
    }
  };

  // ---- phase 2 (per pass P): 13 MFMA steps, taps 2s/2s+1 x 32 ch ----
  auto phase2 = [&](int P) {
    if (!anyact) return;
    const uint4* Bp = (const uint4*)(ws + WS_BFRAG) + P * 13 * 128;
    uint4 b0[2], b1[2];
#pragma unroll
    for (int t = 0; t < 2; ++t) {
      b0[t] = Bp[t * 128 + lane * 2 + 0];
      b1[t] = Bp[t * 128 + lane * 2 + 1];
    }
#pragma unroll
    for (int s = 0; s < 13; ++s) {
      const int sl = s & 1;  // compile-time under full unroll
      uint4 bc0 = b0[sl], bc1 = b1[sl];
      if (s + 2 < 13) {
        b0[sl] = Bp[(s + 2) * 128 + lane * 2 + 0];
        b1[sl] = Bp[(s + 2) * 128 + lane * 2 + 1];
      }
      const int t0 = 2 * s;
      const int t1 = (2 * s + 1 < 25) ? (2 * s + 1) : 24;  // pad: B=0, A reads tap-24 rows
      const unsigned d0 = (unsigned)((t0 / 5) * 30 + t0 % 5) * 16u;
      const unsigned d1 = (unsigned)((t1 / 5) * 30 + t1 % 5) * 16u;
      v8i bop = (v8i){(int)bc0.x, (int)bc0.y, (int)bc0.z, (int)bc0.w,
                      (int)bc1.x, (int)bc1.y, (int)bc1.z, (int)bc1.w};
#pragma unroll
      for (int ti = 0; ti < 3; ++ti) {
        if (!acts[ti]) continue;
        uint4 r0 = *(const uint4*)(smem + vb[ti] + d0);
        uint4 r1 = *(const uint4*)(smem + vb[ti] + d1);
        v8i aop = (v8i){(int)r0.x, (int)r0.y, (int)r0.z, (int)r0.w,
                        (int)r1.x, (int)r1.y, (int)r1.z, (int)r1.w};
        acc[ti] = __builtin_amdgcn_mfma_scale_f32_32x32x64_f8f6f4(
            aop, bop, acc[ti], 0, 0, 0, 0x7F7F7F7F, 0, 0x7F7F7F7F);
      }
    }
  };

  __syncthreads();  // V staged
  phase1(0);
  __syncthreads();
  phase2(0);
  __syncthreads();  // pass-A reads done before pass-B overwrites planes
  phase1(1);
  __syncthreads();
  phase2(1);
  __syncthreads();  // all h1/V reads done; c2T may overwrite [0, 45184)

  const float c2bb = ((const float*)(ws + WS_C2B))[oc] + b2[oc];

  // c2T [32 oc][706 pos] bf16 (aliases h1+V). Packed b32 writes: dword index =
  // oc*353 + pos/2 (pos even). Rows 676..703 land in the pad -> no bounds checks.
  unsigned* c2w = (unsigned*)smem;
  const int oc353 = oc * 353;
#pragma unroll
  for (int ti = 0; ti < 3; ++ti) {
    if (!acts[ti]) continue;
#pragma unroll
    for (int rp = 0; rp < 8; ++rp) {
      int r = 2 * rp;
      int row = (r & 3) + 8 * (r >> 2) + 4 * (lane >> 5);  // row even; row+1 is r+1
      int pos = tb[ti] + row;
      float lo = acc[ti][r] + c2bb, hi = acc[ti][r + 1] + c2bb;
      unsigned pk;
      asm("v_cvt_pk_bf16_f32 %0, %1, %2" : "=v"(pk) : "v"(lo), "v"(hi));
      c2w[oc353 + (pos >> 1)] = pk;
    }
  }
  {
    unsigned short cu = f2bf(c2bb);
    unsigned cupk = (unsigned)cu | ((unsigned)cu << 16);
#pragma unroll
    for (int ti = 0; ti < 3; ++ti) {
      int tf = wid + ti * 8;
      if (tf < 22 && (tf < t_first || tf > t_last)) {
#pragma unroll
        for (int rp = 0; rp < 8; ++rp) {
          int r = 2 * rp;
          int row = (r & 3) + 8 * (r >> 2) + 4 * (lane >> 5);
          int pos = tf * 32 + row;
          c2w[oc353 + (pos >> 1)] = cupk;
        }
      }
    }
  }
  __syncthreads();

  // ---- phase 3: pool2 + spatial mean (paired b32 reads, stride 353) ----
  {
    float* partial = (float*)(smem + SM_PART);
    const unsigned* c2r = (const unsigned*)smem;
    int moc = lane & 31;
    int mi = wid * 2 + (lane >> 5);  // 0..15
    int m353 = moc * 353;
    float ssum = 0.f;
    for (int q = mi; q < 169; q += 16) {
      int py = q / 13, px = q - py * 13;
      int halfp = py * 26 + px;  // (py*2*26 + px*2)/2
      unsigned ua = c2r[m353 + halfp];
      unsigned ub = c2r[m353 + halfp + 13];
      float v00 = bflo(ua), v01 = bfhi(ua);
      float v10 = bflo(ub), v11 = bfhi(ub);
      ssum += fmaxf(fmaxf(v00, v01), fmaxf(v10, v11));
    }
    partial[mi * 32 + moc] = ssum;
  }
  __syncthreads();
  if (tid < 32) {
    const float* partial = (const float*)(smem + SM_PART);
    float s = 0.f;
#pragma unroll
    for (int mi = 0; mi < 16; ++mi) s += partial[mi * 32 + tid];
    ((float*)(smem + SM_HM))[tid] = s * (1.0f / 169.0f);
  }
  __syncthreads();

  // ---- phase 4: FC + ReLU (float4 fcw loads, in-phase) ----
  {
    const float* hm = (const float*)(smem + SM_HM);
    const float4* wrow4 = (const float4*)(fcw + tid * 32);
    float a = fcb[tid];
#pragma unroll
    for (int q = 0; q < 8; ++q) {
      float4 w = wrow4[q];
      a = fmaf(hm[4 * q + 0], w.x, a);
      a = fmaf(hm[4 * q + 1], w.y, a);
      a = fmaf(hm[4 * q + 2], w.z, a);
      a = fmaf(hm[4 * q + 3], w.w, a);
    }
    out[p * 512 + tid] = fmaxf(a, 0.f);
  }
}

extern "C" void kernel_launch(void* const* d_in, const int* in_sizes, int n_in,
                              void* d_out, int out_size, void* d_ws, size_t ws_size,
                              hipStream_t stream) {
  const float* bboxes = (const float*)d_in[0];
  const float* w1 = (const float*)d_in[1];
  const float* b1 = (const float*)d_in[2];
  const float* w2 = (const float*)d_in[3];
  const float* b2 = (const float*)d_in[4];
  const float* fcw = (const float*)d_in[5];
  const float* fcb = (const float*)d_in[6];
  float* out = (float*)d_out;
  unsigned char* ws = (unsigned char*)d_ws;

  hipLaunchKernelGGL(prep_kernel, dim3(107), dim3(256), 0, stream, w1, b1, w2, out, ws);
  hipLaunchKernelGGL(main_kernel, dim3(NPAIRS), dim3(512), 0, stream, bboxes, b2, fcw, fcb, ws, out);
}

// Round 12
// 61.836 us; speedup vs baseline: 7.9458x; 7.9458x over previous
//
#include <hip/hip_runtime.h>
#include <hip/hip_bf16.h>

// SpatialBranch: 1088 box-pair indicator maps -> conv1(2->64,5x5)+pool2 ->
// conv2(64->32,5x5)+pool2 -> spatial mean -> FC(32->512)+ReLU, plus slicing.
//
// Round 12 = revert to R9 structure (R10 fp4 failed numerics, R11 launch-bounds
// squeeze spilled acc -> 922MB scratch) + precomputed pooled-max table:
//  - MV[c][pidY][pidX][64] fp8: pooled conv1 response for pooled pair-states.
//    Q is monotone => Q(max(v)) = max(Q(v)) => bit-identical to R9. The 13
//    possible per-axis pairs of (stz(2p), stz(2p+1)) are enumerated; runtime
//    pid via a 100-byte LUT. Single-channel positions (dominant) become
//    2 LUT bytes + one 64B MV row copy -- uniform, no tier divergence.
//  - Dual-overlap positions (rare) keep the general path, V read from L2.
//  - LDS 81.5KB (h1 57.6 + MV 21.6 + LUT/HM/PART) -> still 2 blocks/CU.
//  - Keeps R9: MX K=64 fp8 MFMA, plane-pair h1 (2x ds_read_b128/tap), 3-deep
//    B prefetch, c2T packed epilogue, tile-aligned zero-row trim, bias folding.

#define NPAIRS 1088
#define FEAT_SZ (NPAIRS * 512)

typedef float f32x16 __attribute__((ext_vector_type(16)));
typedef int v8i __attribute__((ext_vector_type(8)));
typedef float floatx2 __attribute__((ext_vector_type(2)));

// pair-state tables: pid -> (s0, s1), nibble-packed, pid in [0,13)
#define P0C 0x1678955123400ull
#define P1C 0x9067895512340ull

// workspace layout (bytes)
#define WS_V 0            // V fp8 [200 rows][72 B] = 14400 (for dual path, L2)
#define WS_C2B 14400      // 32 f32
#define WS_BFRAG 14528    // 25 taps x 64 lanes x 32B fp8 = 51200
#define WS_MV 65728       // MV fp8 [2][13][13][64] = 21632
#define WS_LUT 87360      // 100 B pid LUT (padded to 112)
// total 87488 bytes of ws

// LDS layout (bytes)
#define H1_PAIR 14400     // one plane-pair: 900 rows x 16B
#define H1_BYTES 57600    // 4 pairs; phase>=3: c2T [32][706] bf16 = 45184 aliases
#define SM_MV 57600       // 21632
#define SM_LUT 79232      // 128
#define SM_HM 79360       // 128
#define SM_PART 79488     // 2048
#define SMEM_BYTES 81536

__device__ __forceinline__ unsigned short f2bf(float f) {
  __hip_bfloat16 h = __float2bfloat16(f);
  unsigned short u;
  __builtin_memcpy(&u, &h, 2);
  return u;
}
__device__ __forceinline__ float bflo(unsigned int u) { return __uint_as_float(u << 16); }
__device__ __forceinline__ float bfhi(unsigned int u) { return __uint_as_float(u & 0xffff0000u); }

__device__ __forceinline__ void fp8x8_to_f32(uint2 u, float* f) {
  floatx2 t;
  t = __builtin_amdgcn_cvt_pk_f32_fp8((int)u.x, false); f[0] = t.x; f[1] = t.y;
  t = __builtin_amdgcn_cvt_pk_f32_fp8((int)u.x, true);  f[2] = t.x; f[3] = t.y;
  t = __builtin_amdgcn_cvt_pk_f32_fp8((int)u.y, false); f[4] = t.x; f[5] = t.y;
  t = __builtin_amdgcn_cvt_pk_f32_fp8((int)u.y, true);  f[6] = t.x; f[7] = t.y;
}

__device__ __forceinline__ unsigned pack_fp8x4(float a, float b, float c, float d) {
  unsigned q = 0;
  q = __builtin_amdgcn_cvt_pk_fp8_f32(a, b, q, false);
  q = __builtin_amdgcn_cvt_pk_fp8_f32(c, d, q, true);
  return q;
}

__device__ __forceinline__ void pair_ij(int k, int* pi, int* pj) {
  int i = 0, rem = k;
  while (rem >= 16 - i) { rem -= 16 - i; ++i; }
  *pi = i;
  *pj = i + 1 + rem;
}

// window state for coordinate z vs interval [a,b): 0 empty, 1..4 left-partial
// (k0=s,k1=5), 5 full, 6..9 right-partial (k0=0,k1=s-5). Valid since b-a>=4.
__device__ __forceinline__ int stz(int z, int a, int b) {
  if (z >= a) {
    if (z >= b) return 0;
    if (z <= b - 5) return 5;
    return 5 + (b - z);
  }
  if (z >= a - 4) return a - z;
  return 0;
}

// rect subsum of 5x5 kernel w for window-state (s_y, s_x)
__device__ __forceinline__ float rectsum(int s_y, int s_x, const float* w) {
  int ky0 = (s_y <= 4) ? s_y : 0;
  int ky1 = (s_y == 0) ? 0 : ((s_y <= 5) ? 5 : s_y - 5);
  int kx0 = (s_x <= 4) ? s_x : 0;
  int kx1 = (s_x == 0) ? 0 : ((s_x <= 5) ? 5 : s_x - 5);
  float v = 0.f;
  for (int ky = ky0; ky < ky1; ++ky)
    for (int kx = kx0; kx < kx1; ++kx) v += w[ky * 5 + kx];
  return v;
}

__global__ void prep_kernel(const float* __restrict__ w1, const float* __restrict__ b1,
                            const float* __restrict__ w2, float* __restrict__ out,
                            unsigned char* __restrict__ ws) {
  int tid = blockIdx.x * blockDim.x + threadIdx.x;

  if (tid < 12800) {
    // V[c][sy][sx][o] fp8 (dual-path table, read from L2 in main)
    int o = tid & 63;
    int q = tid >> 6;
    int sx = q % 10; q /= 10;
    int sy = q % 10;
    int c = q / 10;
    float v = rectsum(sy, sx, w1 + (o * 2 + c) * 25);
    unsigned qv = __builtin_amdgcn_cvt_pk_fp8_f32(v, v, 0, false);
    ((unsigned char*)(ws + WS_V))[(c * 100 + sy * 10 + sx) * 72 + o] = (unsigned char)(qv & 0xFF);
  } else if (tid < 12832) {
    // C2B[oc] = sum_ic b1[ic] * sum_tap w2[oc][ic][tap]
    int oc = tid - 12800;
    float s = 0.f;
    for (int ic = 0; ic < 64; ++ic) {
      const float* wp = w2 + (oc * 64 + ic) * 25;
      float t = 0.f;
      for (int q2 = 0; q2 < 25; ++q2) t += wp[q2];
      s += b1[ic] * t;
    }
    ((float*)(ws + WS_C2B))[oc] = s;
  } else if (tid < 13920) {
    // slicing output (as float values; d_out read back as float32)
    int p = tid - 12832;
    int b = p / 136, k = p % 136, i, j;
    pair_ij(k, &i, &j);
    out[FEAT_SZ + p * 3 + 0] = (float)b;
    out[FEAT_SZ + p * 3 + 1] = (float)i;
    out[FEAT_SZ + p * 3 + 2] = (float)j;
  } else if (tid < 26720) {
    // conv2 B fragments (fp8): dword index = tap*512 + lane*8 + d
    int idx = tid - 13920;          // [0, 12800)
    int d = idx & 7;
    int lane = (idx >> 3) & 63;
    int tap = idx >> 9;
    int n = lane & 31, h = lane >> 5;
    int icb = h * 32 + d * 4;
    float v0 = w2[(n * 64 + icb + 0) * 25 + tap];
    float v1 = w2[(n * 64 + icb + 1) * 25 + tap];
    float v2 = w2[(n * 64 + icb + 2) * 25 + tap];
    float v3 = w2[(n * 64 + icb + 3) * 25 + tap];
    ((unsigned*)(ws + WS_BFRAG))[tap * 512 + lane * 8 + d] = pack_fp8x4(v0, v1, v2, v3);
  } else if (tid < 26820) {
    // pid LUT: (s0,s1) -> pair index, 255 if not a valid pair (never queried)
    int t = tid - 26720;
    int s0 = t / 10, s1 = t % 10;
    int pid = 255;
    for (int i = 0; i < 13; ++i) {
      int a = (int)((P0C >> (4 * i)) & 15ull);
      int b = (int)((P1C >> (4 * i)) & 15ull);
      if (a == s0 && b == s1) pid = i;
    }
    ((unsigned char*)(ws + WS_LUT))[t] = (unsigned char)pid;
  } else if (tid < 26820 + 21632) {
    // MV[c][pidY][pidX][o] fp8 = Q( max_{dy,dx} rectsum(syP[pidY][dy], sxP[pidX][dx]) )
    int m = tid - 26820;
    int o = m & 63;
    int q = m >> 6;
    int pidX = q % 13; q /= 13;
    int pidY = q % 13;
    int c = q / 13;
    int y0 = (int)((P0C >> (4 * pidY)) & 15ull);
    int y1 = (int)((P1C >> (4 * pidY)) & 15ull);
    int x0 = (int)((P0C >> (4 * pidX)) & 15ull);
    int x1 = (int)((P1C >> (4 * pidX)) & 15ull);
    const float* w = w1 + (o * 2 + c) * 25;
    float v = rectsum(y0, x0, w);
    v = fmaxf(v, rectsum(y0, x1, w));
    v = fmaxf(v, rectsum(y1, x0, w));
    v = fmaxf(v, rectsum(y1, x1, w));
    unsigned qv = __builtin_amdgcn_cvt_pk_fp8_f32(v, v, 0, false);
    ((unsigned char*)(ws + WS_MV))[((c * 13 + pidY) * 13 + pidX) * 64 + o] =
        (unsigned char)(qv & 0xFF);
  }
}

__global__ __launch_bounds__(512, 4) void main_kernel(
    const float* __restrict__ bboxes, const float* __restrict__ b2,
    const float* __restrict__ fcw, const float* __restrict__ fcb,
    const unsigned char* __restrict__ ws, float* __restrict__ out) {
  __shared__ __align__(16) unsigned char smem[SMEM_BYTES];
  const int tid = threadIdx.x;
  const int lane = tid & 63;
  const int wid = tid >> 6;
  const int p = blockIdx.x;

  // ---- stage MV + LUT into LDS (21744 B contiguous, coalesced) ----
  {
    const uint4* src = (const uint4*)(ws + WS_MV);
    uint4* dst = (uint4*)(smem + SM_MV);
    for (int i = tid; i < 1359; i += 512) dst[i] = src[i];
  }

  // ---- pair constants (uniform; overlaps the staging) ----
  int b = p / 136, k = p % 136, bi, bj;
  pair_ij(k, &bi, &bj);
  const float* bbA = bboxes + (b * 17 + bi) * 4;
  const float* bbB = bboxes + (b * 17 + bj) * 4;
  int ax[2], ay[2], bx[2], by[2];
  {
    auto cl = [](float v) { int t = (int)ceilf(v); return t < 0 ? 0 : (t > 64 ? 64 : t); };
    ax[0] = cl(bbA[0]); ay[0] = cl(bbA[1]); bx[0] = cl(bbA[2]); by[0] = cl(bbA[3]);
    ax[1] = cl(bbB[0]); ay[1] = cl(bbB[1]); bx[1] = cl(bbB[2]); by[1] = cl(bbB[3]);
  }

  // active conv2 output row range (h1 zero outside support; bias folded -> valid skip)
  int s0a = ay[0] - 4 < 0 ? 0 : ay[0] - 4;
  int s0b = ay[1] - 4 < 0 ? 0 : ay[1] - 4;
  int pre0 = s0a < s0b ? s0a : s0b;
  int e0a = by[0] < 60 ? by[0] : 60;
  int e0b = by[1] < 60 ? by[1] : 60;
  int pre1 = e0a > e0b ? e0a : e0b;
  int pr0 = pre0 >> 1, pr1 = (pre1 - 1) >> 1;
  int or0 = pr0 - 4 < 0 ? 0 : pr0 - 4;
  int or1 = pr1 > 25 ? 25 : pr1;
  int poslo = or0 * 26, poshi = (or1 + 1) * 26;
  int t_first = poslo >> 5;
  int t_last = (poshi - 1) >> 5;  // <= 21

  // h1 rows phase 2 actually reads (TILE-ALIGNED pos range; R7 lesson)
  int pos_end = (t_last + 1) * 32; if (pos_end > 676) pos_end = 676;
  int zr0 = (t_first * 32) / 26;
  int zr1 = (pos_end - 1) / 26 + 4; if (zr1 > 29) zr1 = 29;

  __syncthreads();  // MV + LUT staged

  // ---- phase 1: conv1 + pool1; h1 fp8 plane-pairs, no b1.
  //      single-channel (dominant): LUT -> one MV row copy (bit-identical,
  //      Q monotone). dual overlap (rare): general path, V from L2. ----
  {
    const unsigned char* lut = (const unsigned char*)(smem + SM_LUT);
    const unsigned char* Vg = ws + WS_V;
    for (int pos = tid; pos < 900; pos += 512) {
      int py = pos / 30;
      if (py < zr0 || py > zr1) continue;  // never read by phase 2
      int px = pos - py * 30;
      int oy = py * 2, ox = px * 2;
      int sy[2][2], sx[2][2];
#pragma unroll
      for (int c = 0; c < 2; ++c) {
        sy[c][0] = stz(oy, ay[c], by[c]);
        sy[c][1] = stz(oy + 1, ay[c], by[c]);
        sx[c][0] = stz(ox, ax[c], bx[c]);
        sx[c][1] = stz(ox + 1, ax[c], bx[c]);
      }
      bool e0 = ((sy[0][0] | sy[0][1]) == 0) || ((sx[0][0] | sx[0][1]) == 0);
      bool e1 = ((sy[1][0] | sy[1][1]) == 0) || ((sx[1][0] | sx[1][1]) == 0);
      unsigned hb = (unsigned)pos * 16u;

      if (e0 && e1) {
#pragma unroll
        for (int pp = 0; pp < 4; ++pp)
          *(uint4*)(smem + pp * H1_PAIR + hb) = make_uint4(0u, 0u, 0u, 0u);
        continue;
      }

      if (e0 || e1) {
        // ---- single active channel: pooled-max table row copy ----
        int c = e0 ? 1 : 0;
        int pidY = lut[sy[c][0] * 10 + sy[c][1]];
        int pidX = lut[sx[c][0] * 10 + sx[c][1]];
        unsigned mvb = (unsigned)SM_MV + (unsigned)(((c * 13 + pidY) * 13 + pidX) << 6);
        uint4 q0 = *(const uint4*)(smem + mvb + 0u);
        uint4 q1 = *(const uint4*)(smem + mvb + 16u);
        uint4 q2 = *(const uint4*)(smem + mvb + 32u);
        uint4 q3 = *(const uint4*)(smem + mvb + 48u);
        *(uint4*)(smem + 0 * H1_PAIR + hb) = q0;
        *(uint4*)(smem + 1 * H1_PAIR + hb) = q1;
        *(uint4*)(smem + 2 * H1_PAIR + hb) = q2;
        *(uint4*)(smem + 3 * H1_PAIR + hb) = q3;
        continue;
      }

      // ---- both channels active (overlap region, rare): V from L2 ----
      unsigned r0o[4], r1o[4];
#pragma unroll
      for (int dy = 0; dy < 2; ++dy)
#pragma unroll
        for (int dx = 0; dx < 2; ++dx) {
          r0o[dy * 2 + dx] = (unsigned)(sy[0][dy] * 10 + sx[0][dx]) * 72u;
          r1o[dy * 2 + dx] = 7200u + (unsigned)(sy[1][dy] * 10 + sx[1][dx]) * 72u;
        }
      bool sameAB = (r0o[1] == r0o[0]) & (r0o[2] == r0o[0]) & (r0o[3] == r0o[0]) &
                    (r1o[1] == r1o[0]) & (r1o[2] == r1o[0]) & (r1o[3] == r1o[0]);
#pragma unroll
      for (int pp = 0; pp < 4; ++pp) {
        unsigned qv[4];
#pragma unroll
        for (int gg = 0; gg < 2; ++gg) {
          int g = pp * 2 + gg;
          float mx[8];
          if (sameAB) {
            uint2 u0 = *(const uint2*)(Vg + r0o[0] + g * 8u);
            uint2 u1 = *(const uint2*)(Vg + r1o[0] + g * 8u);
            float a[8], c[8];
            fp8x8_to_f32(u0, a);
            fp8x8_to_f32(u1, c);
#pragma unroll
            for (int d = 0; d < 8; ++d) mx[d] = a[d] + c[d];
          } else {
#pragma unroll
            for (int sp = 0; sp < 4; ++sp) {
              uint2 u0 = *(const uint2*)(Vg + r0o[sp] + g * 8u);
              uint2 u1 = *(const uint2*)(Vg + r1o[sp] + g * 8u);
              float a[8], c[8];
              fp8x8_to_f32(u0, a);
              fp8x8_to_f32(u1, c);
#pragma unroll
              for (int d = 0; d < 8; ++d) {
                float v = a[d] + c[d];
                mx[d] = (sp == 0) ? v : fmaxf(mx[d], v);
              }
            }
          }
          qv[2 * gg + 0] = pack_fp8x4(mx[0], mx[1], mx[2], mx[3]);
          qv[2 * gg + 1] = pack_fp8x4(mx[4], mx[5], mx[6], mx[7]);
        }
        *(uint4*)(smem + pp * H1_PAIR + hb) = make_uint4(qv[0], qv[1], qv[2], qv[3]);
      }
    }
  }
  __syncthreads();

  // ---- phase 2: conv2 as K=64 MX fp8 MFMA implicit GEMM over ACTIVE tiles ----
  const int oc = lane & 31;
  const float c2bb = ((const float*)(ws + WS_C2B))[oc] + b2[oc];

  // compact assignment over active tiles: t = t_first + wid + ti*8
  int tb[3]; int acts[3]; unsigned vb[3]; bool anyact = false;
  const unsigned hvo16 = (unsigned)(lane >> 5) * (2u * H1_PAIR);
#pragma unroll
  for (int ti = 0; ti < 3; ++ti) {
    int t = t_first + wid + ti * 8;
    bool a = (t <= t_last);
    acts[ti] = __builtin_amdgcn_readfirstlane(a ? 1 : 0);  // wave-uniform -> SGPR
    anyact |= a;
    tb[ti] = t * 32;
    int pos = tb[ti] + (lane & 31);
    if (pos > 675) pos = 675;
    int oy2 = pos / 26, ox2 = pos - oy2 * 26;
    vb[ti] = (unsigned)(oy2 * 30 + ox2) * 16u + hvo16;  // inactive: never read
  }

  f32x16 acc[3];
#pragma unroll
  for (int ti = 0; ti < 3; ++ti)
#pragma unroll
    for (int r = 0; r < 16; ++r) acc[ti][r] = 0.f;

  if (anyact) {
    const uint4* Bp = (const uint4*)(ws + WS_BFRAG);
    uint4 b0[3], b1[3];
#pragma unroll
    for (int t = 0; t < 3; ++t) {
      b0[t] = Bp[t * 128 + lane * 2 + 0];
      b1[t] = Bp[t * 128 + lane * 2 + 1];
    }
#pragma unroll
    for (int t = 0; t < 25; ++t) {
      const int sl = t % 3;  // compile-time under full unroll
      uint4 bc0 = b0[sl], bc1 = b1[sl];
      if (t + 3 < 25) {
        b0[sl] = Bp[(t + 3) * 128 + lane * 2 + 0];
        b1[sl] = Bp[(t + 3) * 128 + lane * 2 + 1];
      }
      const unsigned dtap16 = (unsigned)((t / 5) * 30 + (t % 5)) * 16u;
      v8i bop = (v8i){(int)bc0.x, (int)bc0.y, (int)bc0.z, (int)bc0.w,
                      (int)bc1.x, (int)bc1.y, (int)bc1.z, (int)bc1.w};
#pragma unroll
      for (int ti = 0; ti < 3; ++ti) {
        if (!acts[ti]) continue;
        uint4 r0 = *(const uint4*)(smem + vb[ti] + 0u * H1_PAIR + dtap16);
        uint4 r1 = *(const uint4*)(smem + vb[ti] + 1u * H1_PAIR + dtap16);
        v8i aop = (v8i){(int)r0.x, (int)r0.y, (int)r0.z, (int)r0.w,
                        (int)r1.x, (int)r1.y, (int)r1.z, (int)r1.w};
        acc[ti] = __builtin_amdgcn_mfma_scale_f32_32x32x64_f8f6f4(
            aop, bop, acc[ti], 0, 0, 0, 0x7F7F7F7F, 0, 0x7F7F7F7F);
      }
    }
  }
  __syncthreads();  // all h1 reads done; c2T may now overwrite h1's LDS region

  // c2T [32 oc][706 pos] bf16 (aliases h1). Packed b32 writes: dword index =
  // oc*353 + pos/2 (pos even). Rows 676..703 land in the pad -> no bounds checks.
  unsigned* c2w = (unsigned*)smem;
  const int oc353 = oc * 353;
#pragma unroll
  for (int ti = 0; ti < 3; ++ti) {
    if (!acts[ti]) continue;
#pragma unroll
    for (int rp = 0; rp < 8; ++rp) {
      int r = 2 * rp;
      int row = (r & 3) + 8 * (r >> 2) + 4 * (lane >> 5);  // row even; row+1 is r+1
      int pos = tb[ti] + row;
      float lo = acc[ti][r] + c2bb, hi = acc[ti][r + 1] + c2bb;
      unsigned pk;
      asm("v_cvt_pk_bf16_f32 %0, %1, %2" : "=v"(pk) : "v"(lo), "v"(hi));
      c2w[oc353 + (pos >> 1)] = pk;
    }
  }
  {
    unsigned short cu = f2bf(c2bb);
    unsigned cupk = (unsigned)cu | ((unsigned)cu << 16);
#pragma unroll
    for (int ti = 0; ti < 3; ++ti) {
      int tf = wid + ti * 8;
      if (tf < 22 && (tf < t_first || tf > t_last)) {
#pragma unroll
        for (int rp = 0; rp < 8; ++rp) {
          int r = 2 * rp;
          int row = (r & 3) + 8 * (r >> 2) + 4 * (lane >> 5);
          int pos = tf * 32 + row;
          c2w[oc353 + (pos >> 1)] = cupk;
        }
      }
    }
  }
  __syncthreads();

  // ---- phase 3: pool2 + spatial mean (paired b32 reads, stride 353) ----
  {
    float* partial = (float*)(smem + SM_PART);
    const unsigned* c2r = (const unsigned*)smem;
    int moc = lane & 31;
    int mi = wid * 2 + (lane >> 5);  // 0..15
    int m353 = moc * 353;
    float ssum = 0.f;
    for (int q = mi; q < 169; q += 16) {
      int py = q / 13, px = q - py * 13;
      int halfp = py * 26 + px;  // (py*2*26 + px*2)/2
      unsigned ua = c2r[m353 + halfp];
      unsigned ub = c2r[m353 + halfp + 13];
      float v00 = bflo(ua), v01 = bfhi(ua);
      float v10 = bflo(ub), v11 = bfhi(ub);
      ssum += fmaxf(fmaxf(v00, v01), fmaxf(v10, v11));
    }
    partial[mi * 32 + moc] = ssum;
  }
  __syncthreads();
  if (tid < 32) {
    const float* partial = (const float*)(smem + SM_PART);
    float s = 0.f;
#pragma unroll
    for (int mi = 0; mi < 16; ++mi) s += partial[mi * 32 + tid];
    ((float*)(smem + SM_HM))[tid] = s * (1.0f / 169.0f);
  }
  __syncthreads();

  // ---- phase 4: FC + ReLU (float4 fcw loads, in-phase) ----
  {
    const float* hm = (const float*)(smem + SM_HM);
    const float4* wrow4 = (const float4*)(fcw + tid * 32);
    float a = fcb[tid];
#pragma unroll
    for (int q = 0; q < 8; ++q) {
      float4 w = wrow4[q];
      a = fmaf(hm[4 * q + 0], w.x, a);
      a = fmaf(hm[4 * q + 1], w.y, a);
      a = fmaf(hm[4 * q + 2], w.z, a);
      a = fmaf(hm[4 * q + 3], w.w, a);
    }
    out[p * 512 + tid] = fmaxf(a, 0.f);
  }
}

extern "C" void kernel_launch(void* const* d_in, const int* in_sizes, int n_in,
                              void* d_out, int out_size, void* d_ws, size_t ws_size,
                              hipStream_t stream) {
  const float* bboxes = (const float*)d_in[0];
  const float* w1 = (const float*)d_in[1];
  const float* b1 = (const float*)d_in[2];
  const float* w2 = (const float*)d_in[3];
  const float* b2 = (const float*)d_in[4];
  const float* fcw = (const float*)d_in[5];
  const float* fcb = (const float*)d_in[6];
  float* out = (float*)d_out;
  unsigned char* ws = (unsigned char*)d_ws;

  hipLaunchKernelGGL(prep_kernel, dim3(190), dim3(256), 0, stream, w1, b1, w2, out, ws);
  hipLaunchKernelGGL(main_kernel, dim3(NPAIRS), dim3(512), 0, stream, bboxes, b2, fcw, fcb, ws, out);
}